// Round 1
// baseline (400.250 us; speedup 1.0000x reference)
//
#include <hip/hip_runtime.h>
#include <math.h>

#define ALPHA 32.0f
#define MRG 0.1f
#define STAT_WEIGHT 0.01f
#define STAT_ADJ_W 0.15f
#define COS_EPS 1e-8f

// ---------------- K1: Xn = l2_norm(X), one block per row, D=128 ----------------
__global__ void k_norm_x(const float* __restrict__ X, float* __restrict__ Xn) {
    int b = blockIdx.x, d = threadIdx.x;
    __shared__ float red[128];
    float v = X[b * 128 + d];
    red[d] = v * v;
    __syncthreads();
    #pragma unroll
    for (int s = 64; s > 0; s >>= 1) {
        if (d < s) red[d] += red[d + s];
        __syncthreads();
    }
    Xn[b * 128 + d] = v / sqrtf(red[0] + 1e-12f);
}

// ---------------- K2: per-present-class stats -> adj[c], num_valid -------------
// One block per sample b (duplicate classes recompute identical adj: benign).
__global__ void k_stats(const float* __restrict__ proxies, const float* __restrict__ cc,
                        const float* __restrict__ Xn, const int* __restrict__ T,
                        float* __restrict__ adj, float* __restrict__ scal,
                        int B, int D) {
    int b = blockIdx.x, d = threadIdx.x;
    int c = T[b];
    __shared__ float r1[128], r2[128], r3[128];
    float p  = proxies[(size_t)c * D + d];
    float cv = cc[(size_t)c * D + d];
    r1[d] = p * p; r2[d] = cv * cv; r3[d] = p * cv;
    __syncthreads();
    #pragma unroll
    for (int s = 64; s > 0; s >>= 1) {
        if (d < s) { r1[d] += r1[d + s]; r2[d] += r2[d + s]; r3[d] += r3[d + s]; }
        __syncthreads();
    }
    float s2 = r1[0], c2 = r2[0], pc = r3[0];
    float inv = 1.0f / sqrtf(s2 + 1e-12f);       // Pn = p * inv
    float pn2 = s2 * inv * inv;                  // sum(Pn^2)
    float pnorm = fmaxf(sqrtf(pn2), COS_EPS);
    float cnorm = fmaxf(sqrtf(c2), COS_EPS);
    float censim = (pc * inv) / (pnorm * cnorm);
    __syncthreads();

    // scan all samples of this class
    float sd = 0.f, qd = 0.f;
    int cnt = 0, minj = -1;
    for (int j = 0; j < B; ++j) {
        if (T[j] == c) {
            float x = Xn[(size_t)j * D + d];
            sd += x; qd += x * x;
            if (minj < 0) minj = j;
            cnt++;
        }
    }
    float fc = (float)cnt;                        // cnt >= 1 (class c came from T[b])
    float m = sd / fc;
    float var = qd / fc - m * m;
    var = fminf(fmaxf(var, 1e-6f), 10.0f);
    r1[d] = var;
    __syncthreads();
    #pragma unroll
    for (int s = 64; s > 0; s >>= 1) {
        if (d < s) r1[d] += r1[d + s];
        __syncthreads();
    }
    if (d == 0) {
        float mvar = r1[0] / (float)D;
        float vw = 1.0f / (1.0f + mvar);
        adj[c] = censim * vw * STAT_ADJ_W;
        if (minj == b) atomicAdd(&scal[3], 1.0f);   // num_valid: first occurrence
    }
}

// ---------------- K3: sum |class_centers| -> scal[2] ---------------------------
__global__ void k_absum(const float* __restrict__ cc, float* __restrict__ scal, int n4) {
    int i = blockIdx.x * blockDim.x + threadIdx.x;
    int stride = gridDim.x * blockDim.x;
    float s = 0.f;
    for (; i < n4; i += stride) {
        float4 v = ((const float4*)cc)[i];
        s += fabsf(v.x) + fabsf(v.y) + fabsf(v.z) + fabsf(v.w);
    }
    #pragma unroll
    for (int off = 32; off > 0; off >>= 1) s += __shfl_down(s, off);
    __shared__ float ws_[4];
    int lane = threadIdx.x & 63, wid = threadIdx.x >> 6;
    if (lane == 0) ws_[wid] = s;
    __syncthreads();
    if (threadIdx.x == 0) atomicAdd(&scal[2], ws_[0] + ws_[1] + ws_[2] + ws_[3]);
}

// ---------------- K4: GEMM (512 x C x 128) + fused exp/log1p reduction ---------
// Block: 64 classes x all B rows. LDS tiles stored transposed [K][64] so the
// 4x4-fragment reads are ds_read_b128 with 2-way bank aliasing (free per m136).
__launch_bounds__(256, 2)
__global__ void k_main(const float* __restrict__ proxies, const float* __restrict__ Xn,
                       const int* __restrict__ T, const float* __restrict__ adj,
                       float* __restrict__ scal, int B, int C) {
    __shared__ float PsT[128][64];   // 32 KB  [k][class]
    __shared__ float XsT[128][64];   // 32 KB  [k][row]
    const int tid = threadIdx.x;
    const int c0 = blockIdx.x * 64;
    const int tr4 = tid & 15, tc4 = tid >> 4;   // 16 row-groups x 16 col-groups

    // stage proxies tile (transposed write; conflicts here are once-per-block)
    #pragma unroll
    for (int i = 0; i < 8; ++i) {
        int lin = i * 256 + tid;
        int row = lin >> 5, col4 = lin & 31;
        int cg = c0 + row; if (cg >= C) cg = C - 1;
        const float4 p = *(const float4*)(proxies + (size_t)cg * 128 + col4 * 4);
        PsT[col4 * 4 + 0][row] = p.x;
        PsT[col4 * 4 + 1][row] = p.y;
        PsT[col4 * 4 + 2][row] = p.z;
        PsT[col4 * 4 + 3][row] = p.w;
    }
    __syncthreads();
    // normalize each proxy row (column of PsT)
    if (tid < 64) {
        float s2 = 0.f;
        #pragma unroll 8
        for (int k = 0; k < 128; ++k) { float v = PsT[k][tid]; s2 += v * v; }
        float sc = 1.0f / sqrtf(s2 + 1e-12f);
        #pragma unroll 8
        for (int k = 0; k < 128; ++k) PsT[k][tid] *= sc;
    }
    float adj_r[4];
    #pragma unroll
    for (int j = 0; j < 4; ++j) {
        int cg = c0 + tc4 * 4 + j;
        adj_r[j] = (cg < C) ? adj[cg] : 0.f;
    }
    float npart[4] = {0, 0, 0, 0}, ppart[4] = {0, 0, 0, 0};
    __syncthreads();

    const int nchunk = B >> 6;   // B=512 -> 8
    for (int chunk = 0; chunk < nchunk; ++chunk) {
        #pragma unroll
        for (int i = 0; i < 8; ++i) {
            int lin = i * 256 + tid;
            int row = lin >> 5, col4 = lin & 31;
            const float4 x = *(const float4*)(Xn + (size_t)(chunk * 64 + row) * 128 + col4 * 4);
            XsT[col4 * 4 + 0][row] = x.x;
            XsT[col4 * 4 + 1][row] = x.y;
            XsT[col4 * 4 + 2][row] = x.z;
            XsT[col4 * 4 + 3][row] = x.w;
        }
        __syncthreads();

        float acc[4][4] = {{0.f}};
        #pragma unroll 4
        for (int k = 0; k < 128; k += 4) {
            #pragma unroll
            for (int kk = 0; kk < 4; ++kk) {
                float4 a = *(const float4*)&XsT[k + kk][tr4 * 4];   // 4 rows
                float4 b = *(const float4*)&PsT[k + kk][tc4 * 4];   // 4 classes
                acc[0][0] += a.x * b.x; acc[0][1] += a.x * b.y; acc[0][2] += a.x * b.z; acc[0][3] += a.x * b.w;
                acc[1][0] += a.y * b.x; acc[1][1] += a.y * b.y; acc[1][2] += a.y * b.z; acc[1][3] += a.y * b.w;
                acc[2][0] += a.z * b.x; acc[2][1] += a.z * b.y; acc[2][2] += a.z * b.z; acc[2][3] += a.z * b.w;
                acc[3][0] += a.w * b.x; acc[3][1] += a.w * b.y; acc[3][2] += a.w * b.z; acc[3][3] += a.w * b.w;
            }
        }

        #pragma unroll
        for (int r = 0; r < 4; ++r) {
            int rg = chunk * 64 + tr4 * 4 + r;
            int tv = T[rg];                       // 2 KB array, L1-hot
            #pragma unroll
            for (int j = 0; j < 4; ++j) {
                int cg = c0 + tc4 * 4 + j;
                if (cg < C) {
                    float comb = acc[r][j] + adj_r[j];
                    if (tv == cg) ppart[j] += __expf(-ALPHA * (comb - MRG));
                    else          npart[j] += __expf( ALPHA * (comb + MRG));
                }
            }
        }
        __syncthreads();
    }

    // reduce the 16 row-group lanes sharing each class (contiguous 16-lane groups)
    #pragma unroll
    for (int j = 0; j < 4; ++j) {
        #pragma unroll
        for (int off = 1; off < 16; off <<= 1) {
            npart[j] += __shfl_xor(npart[j], off);
            ppart[j] += __shfl_xor(ppart[j], off);
        }
    }
    if (tr4 == 0) {
        float ln = 0.f, lp = 0.f;
        #pragma unroll
        for (int j = 0; j < 4; ++j) {
            int cg = c0 + tc4 * 4 + j;
            if (cg < C) { ln += log1pf(npart[j]); lp += log1pf(ppart[j]); }
        }
        atomicAdd(&scal[1], ln);   // sum log1p(N_sim_sum)
        atomicAdd(&scal[0], lp);   // sum log1p(P_sim_sum)  (0 for empty classes)
    }
}

// ---------------- K5: finalize --------------------------------------------------
__global__ void k_final(const float* __restrict__ scal, float* __restrict__ out,
                        int C, int D) {
    float num_valid = scal[3];
    float center_reg = scal[2] / ((float)C * (float)D);
    out[0] = scal[0] / num_valid + scal[1] / (float)C + STAT_WEIGHT * center_reg;
}

extern "C" void kernel_launch(void* const* d_in, const int* in_sizes, int n_in,
                              void* d_out, int out_size, void* d_ws, size_t ws_size,
                              hipStream_t stream) {
    const float* X       = (const float*)d_in[0];
    const int*   T       = (const int*)d_in[1];
    const float* proxies = (const float*)d_in[2];
    const float* cc      = (const float*)d_in[3];
    float* out = (float*)d_out;

    const int B = in_sizes[1];            // 512
    const int D = in_sizes[0] / B;        // 128
    const int C = in_sizes[2] / D;        // 50000

    float* Xn   = (float*)d_ws;           // B*D floats
    float* adj  = Xn + (size_t)B * D;     // C floats
    float* scal = adj + C;                // [0]=S_pos [1]=S_neg [2]=abs_sum [3]=num_valid

    hipMemsetAsync(adj, 0, ((size_t)C + 4) * sizeof(float), stream);

    k_norm_x<<<B, D, 0, stream>>>(X, Xn);
    k_stats<<<B, D, 0, stream>>>(proxies, cc, Xn, T, adj, scal, B, D);
    k_absum<<<1024, 256, 0, stream>>>(cc, scal, C * D / 4);
    k_main<<<(C + 63) / 64, 256, 0, stream>>>(proxies, Xn, T, adj, scal, B, C);
    k_final<<<1, 1, 0, stream>>>(scal, out, C, D);
}

// Round 2
// 176.122 us; speedup vs baseline: 2.2726x; 2.2726x over previous
//
#include <hip/hip_runtime.h>
#include <math.h>

#define ALPHA 32.0f
#define MRG 0.1f
#define STAT_WEIGHT 0.01f
#define STAT_ADJ_W 0.15f
#define COS_EPS 1e-8f

typedef __attribute__((ext_vector_type(8))) short bf16x8;
typedef __attribute__((ext_vector_type(4))) float f32x4;

__device__ __forceinline__ ushort f2bf(float f) {
    unsigned u = __float_as_uint(f);
    unsigned r = (u + 0x7FFFu + ((u >> 16) & 1u)) >> 16;   // RNE
    return (ushort)r;
}

// ---------------- K1: Xn = l2_norm(X) -> fp32 + bf16 copies --------------------
__global__ void k_norm_x(const float* __restrict__ X, float* __restrict__ Xn,
                         ushort* __restrict__ Xn16) {
    int b = blockIdx.x, d = threadIdx.x;
    __shared__ float red[128];
    float v = X[b * 128 + d];
    red[d] = v * v;
    __syncthreads();
    #pragma unroll
    for (int s = 64; s > 0; s >>= 1) {
        if (d < s) red[d] += red[d + s];
        __syncthreads();
    }
    float xn = v / sqrtf(red[0] + 1e-12f);
    Xn[b * 128 + d] = xn;
    Xn16[b * 128 + d] = f2bf(xn);
}

// ---------------- K2: per-present-class stats -> adj[c], num_valid -------------
__global__ void k_stats(const float* __restrict__ proxies, const float* __restrict__ cc,
                        const float* __restrict__ Xn, const int* __restrict__ T,
                        float* __restrict__ adj, float* __restrict__ scal,
                        int B, int D) {
    int b = blockIdx.x, d = threadIdx.x;
    int c = T[b];
    __shared__ float r1[128], r2[128], r3[128];
    float p  = proxies[(size_t)c * D + d];
    float cv = cc[(size_t)c * D + d];
    r1[d] = p * p; r2[d] = cv * cv; r3[d] = p * cv;
    __syncthreads();
    #pragma unroll
    for (int s = 64; s > 0; s >>= 1) {
        if (d < s) { r1[d] += r1[d + s]; r2[d] += r2[d + s]; r3[d] += r3[d + s]; }
        __syncthreads();
    }
    float s2 = r1[0], c2 = r2[0], pc = r3[0];
    float inv = 1.0f / sqrtf(s2 + 1e-12f);
    float pn2 = s2 * inv * inv;
    float pnorm = fmaxf(sqrtf(pn2), COS_EPS);
    float cnorm = fmaxf(sqrtf(c2), COS_EPS);
    float censim = (pc * inv) / (pnorm * cnorm);
    __syncthreads();

    float sd = 0.f, qd = 0.f;
    int cnt = 0, minj = -1;
    for (int j = 0; j < B; ++j) {
        if (T[j] == c) {
            float x = Xn[(size_t)j * D + d];
            sd += x; qd += x * x;
            if (minj < 0) minj = j;
            cnt++;
        }
    }
    float fc = (float)cnt;
    float m = sd / fc;
    float var = qd / fc - m * m;
    var = fminf(fmaxf(var, 1e-6f), 10.0f);
    r1[d] = var;
    __syncthreads();
    #pragma unroll
    for (int s = 64; s > 0; s >>= 1) {
        if (d < s) r1[d] += r1[d + s];
        __syncthreads();
    }
    if (d == 0) {
        float mvar = r1[0] / (float)D;
        float vw = 1.0f / (1.0f + mvar);
        adj[c] = censim * vw * STAT_ADJ_W;
        if (minj == b) atomicAdd(&scal[3], 1.0f);
    }
}

// ---------------- K3: sum |class_centers| -> scal[2] ---------------------------
__global__ void k_absum(const float* __restrict__ cc, float* __restrict__ scal, int n4) {
    int i = blockIdx.x * blockDim.x + threadIdx.x;
    int stride = gridDim.x * blockDim.x;
    float s = 0.f;
    for (; i < n4; i += stride) {
        float4 v = ((const float4*)cc)[i];
        s += fabsf(v.x) + fabsf(v.y) + fabsf(v.z) + fabsf(v.w);
    }
    #pragma unroll
    for (int off = 32; off > 0; off >>= 1) s += __shfl_down(s, off);
    __shared__ float ws_[4];
    int lane = threadIdx.x & 63, wid = threadIdx.x >> 6;
    if (lane == 0) ws_[wid] = s;
    __syncthreads();
    if (threadIdx.x == 0) atomicAdd(&scal[2], ws_[0] + ws_[1] + ws_[2] + ws_[3]);
}

// ---------------- K4: bf16 MFMA GEMM (512 x C x 128) + fused epilogue ----------
// Block: 64 classes x all B rows (8 chunks of 64). 4 waves; wave w owns rows
// [w*16, w*16+16) of each chunk, all 64 classes (4 MFMA tiles in N).
// B-fragments (Pn) hoisted to registers; A staged per chunk, padded stride 136
// ushort (272 B) -> uniform bank distribution on ds_read_b128.
__launch_bounds__(256, 3)
__global__ void k_main(const float* __restrict__ proxies, const ushort* __restrict__ Xn16,
                       const int* __restrict__ T, const float* __restrict__ adj,
                       float* __restrict__ scal, int B, int C) {
    __shared__ ushort Ps[64][136];   // Pn tile, bf16, [class][k]
    __shared__ ushort Xs[64][136];   // Xn chunk, bf16, [row][k]
    __shared__ int    Tl[512];
    __shared__ float  Pred[4][64], Nred[4][64];

    const int tid  = threadIdx.x;
    const int lane = tid & 63;
    const int wv   = tid >> 6;        // wave 0..3
    const int nlo  = lane & 15;       // col within tile / A row within wave window
    const int quad = lane >> 4;
    const int c0   = blockIdx.x * 64;

    // stage T
    Tl[tid] = T[tid];
    Tl[tid + 256] = T[tid + 256];

    // ---- normalize 64 proxy rows -> bf16 Ps ----
    {
        int cls = tid >> 2;           // 0..63
        int q   = tid & 3;            // quarter of K
        int cg  = c0 + cls; if (cg >= C) cg = C - 1;
        const float4* src = (const float4*)(proxies + (size_t)cg * 128 + q * 32);
        float s2 = 0.f;
        #pragma unroll
        for (int i = 0; i < 8; ++i) {
            float4 v = src[i];
            s2 += v.x * v.x + v.y * v.y + v.z * v.z + v.w * v.w;
        }
        s2 += __shfl_xor(s2, 1);
        s2 += __shfl_xor(s2, 2);
        float sc = 1.0f / sqrtf(s2 + 1e-12f);
        #pragma unroll
        for (int i = 0; i < 8; ++i) {
            float4 v = src[i];   // L1-hot reload
            ushort4 o;
            o.x = f2bf(v.x * sc); o.y = f2bf(v.y * sc);
            o.z = f2bf(v.z * sc); o.w = f2bf(v.w * sc);
            *(ushort4*)&Ps[cls][q * 32 + i * 4] = o;
        }
    }
    __syncthreads();

    // ---- hoist B-fragments: [tile][kstep], each 8 bf16 ----
    bf16x8 bfr[4][4];
    #pragma unroll
    for (int t = 0; t < 4; ++t)
        #pragma unroll
        for (int ks = 0; ks < 4; ++ks)
            bfr[t][ks] = *(const bf16x8*)&Ps[t * 16 + nlo][ks * 32 + quad * 8];

    float adjv[4];
    #pragma unroll
    for (int t = 0; t < 4; ++t) {
        int cg = c0 + t * 16 + nlo;
        adjv[t] = (cg < C) ? adj[cg] : 0.f;
    }

    float pp[4] = {0, 0, 0, 0}, np[4] = {0, 0, 0, 0};
    __syncthreads();

    const int nchunk = B >> 6;   // 8
    for (int chunk = 0; chunk < nchunk; ++chunk) {
        // stage 64x128 bf16 rows of Xn
        #pragma unroll
        for (int i = 0; i < 4; ++i) {
            int lin = i * 256 + tid;
            int row = lin >> 4, seg = lin & 15;
            *(uint4*)&Xs[row][seg * 8] =
                *(const uint4*)(Xn16 + (size_t)(chunk * 64 + row) * 128 + seg * 8);
        }
        __syncthreads();

        f32x4 acc[4] = {{0,0,0,0},{0,0,0,0},{0,0,0,0},{0,0,0,0}};
        #pragma unroll
        for (int ks = 0; ks < 4; ++ks) {
            bf16x8 af = *(const bf16x8*)&Xs[wv * 16 + nlo][ks * 32 + quad * 8];
            #pragma unroll
            for (int t = 0; t < 4; ++t)
                acc[t] = __builtin_amdgcn_mfma_f32_16x16x32_bf16(af, bfr[t][ks], acc[t], 0, 0, 0);
        }

        // epilogue: rows = chunk*64 + wv*16 + quad*4 + r ; col = c0 + t*16 + nlo
        int4 tv4 = *(const int4*)&Tl[chunk * 64 + wv * 16 + quad * 4];
        int tvs[4] = {tv4.x, tv4.y, tv4.z, tv4.w};
        #pragma unroll
        for (int t = 0; t < 4; ++t) {
            int cls = c0 + t * 16 + nlo;
            if (cls < C) {
                #pragma unroll
                for (int r = 0; r < 4; ++r) {
                    float comb = acc[t][r] + adjv[t];
                    if (tvs[r] == cls) pp[t] += __expf(-ALPHA * (comb - MRG));
                    else               np[t] += __expf( ALPHA * (comb + MRG));
                }
            }
        }
        __syncthreads();
    }

    // reduce over quad (rows within wave window)
    #pragma unroll
    for (int t = 0; t < 4; ++t) {
        #pragma unroll
        for (int off = 16; off < 64; off <<= 1) {
            pp[t] += __shfl_xor(pp[t], off);
            np[t] += __shfl_xor(np[t], off);
        }
    }
    if (lane < 16) {
        #pragma unroll
        for (int t = 0; t < 4; ++t) {
            Pred[wv][t * 16 + lane] = pp[t];
            Nred[wv][t * 16 + lane] = np[t];
        }
    }
    __syncthreads();
    if (tid < 64) {
        float lp = 0.f, ln = 0.f;
        int cls = c0 + tid;
        if (cls < C) {
            float ps = Pred[0][tid] + Pred[1][tid] + Pred[2][tid] + Pred[3][tid];
            float ns = Nred[0][tid] + Nred[1][tid] + Nred[2][tid] + Nred[3][tid];
            lp = log1pf(ps);      // ps==0 for sample-less classes -> contributes 0
            ln = log1pf(ns);
        }
        #pragma unroll
        for (int off = 32; off > 0; off >>= 1) {
            lp += __shfl_down(lp, off);
            ln += __shfl_down(ln, off);
        }
        if (tid == 0) {
            atomicAdd(&scal[0], lp);
            atomicAdd(&scal[1], ln);
        }
    }
}

// ---------------- K5: finalize --------------------------------------------------
__global__ void k_final(const float* __restrict__ scal, float* __restrict__ out,
                        int C, int D) {
    float num_valid = scal[3];
    float center_reg = scal[2] / ((float)C * (float)D);
    out[0] = scal[0] / num_valid + scal[1] / (float)C + STAT_WEIGHT * center_reg;
}

extern "C" void kernel_launch(void* const* d_in, const int* in_sizes, int n_in,
                              void* d_out, int out_size, void* d_ws, size_t ws_size,
                              hipStream_t stream) {
    const float* X       = (const float*)d_in[0];
    const int*   T       = (const int*)d_in[1];
    const float* proxies = (const float*)d_in[2];
    const float* cc      = (const float*)d_in[3];
    float* out = (float*)d_out;

    const int B = in_sizes[1];            // 512
    const int D = in_sizes[0] / B;        // 128
    const int C = in_sizes[2] / D;        // 50000

    float* Xn   = (float*)d_ws;                       // B*D fp32
    float* adj  = Xn + (size_t)B * D;                 // C fp32
    float* scal = adj + C;                            // 8 fp32
    size_t off  = (((size_t)B * D + C + 8) * 4 + 15) & ~(size_t)15;
    ushort* Xn16 = (ushort*)((char*)d_ws + off);      // B*D bf16

    hipMemsetAsync(adj, 0, ((size_t)C + 8) * sizeof(float), stream);

    k_norm_x<<<B, D, 0, stream>>>(X, Xn, Xn16);
    k_stats<<<B, D, 0, stream>>>(proxies, cc, Xn, T, adj, scal, B, D);
    k_absum<<<1024, 256, 0, stream>>>(cc, scal, C * D / 4);
    k_main<<<(C + 63) / 64, 256, 0, stream>>>(proxies, Xn16, T, adj, scal, B, C);
    k_final<<<1, 1, 0, stream>>>(scal, out, C, D);
}